// Round 1
// baseline (1031.969 us; speedup 1.0000x reference)
//
#include <hip/hip_runtime.h>
#include <math.h>

#define NN 20000
#define CC 512

__device__ __forceinline__ float eluf(float x) { return x > 0.f ? x : expm1f(x); }

// ---------------- zero ----------------
__global__ void k_zero(float4* __restrict__ p, int n4) {
  int i = blockIdx.x * blockDim.x + threadIdx.x;
  if (i < n4) p[i] = make_float4(0.f, 0.f, 0.f, 0.f);
}

// ---------------- CSR build ----------------
__global__ void k_count(const int* __restrict__ key, int n, int* __restrict__ cnt) {
  int i = blockIdx.x * blockDim.x + threadIdx.x;
  if (i < n) atomicAdd(&cnt[key[i]], 1);
}

__global__ void k_dinv(const int* __restrict__ deg, int n, float* __restrict__ dinv) {
  int i = blockIdx.x * blockDim.x + threadIdx.x;
  if (i < n) dinv[i] = rsqrtf((float)(deg[i] + 1));  // +1 self-loop; deg>=1 always
}

__global__ __launch_bounds__(1024) void k_scan(const int* __restrict__ counts, int n,
                                               int* __restrict__ rowptr) {
  __shared__ int part[1024];
  int tid = threadIdx.x;
  int chunk = (n + 1023) >> 10;
  int beg = tid * chunk;
  int fin = beg + chunk; if (fin > n) fin = n;
  int s = 0;
  for (int i = beg; i < fin; ++i) s += counts[i];
  part[tid] = s;
  __syncthreads();
  for (int off = 1; off < 1024; off <<= 1) {
    int v = (tid >= off) ? part[tid - off] : 0;
    __syncthreads();
    part[tid] += v;
    __syncthreads();
  }
  int base = (tid == 0) ? 0 : part[tid - 1];
  for (int i = beg; i < fin; ++i) { rowptr[i] = base; base += counts[i]; }
  if (tid == 1023) rowptr[n] = part[1023];
}

__global__ void k_scatter_edges(const int* __restrict__ src, const int* __restrict__ dst, int n,
                                const int* __restrict__ rowptr, int* __restrict__ fill,
                                const float* __restrict__ dinv,
                                int* __restrict__ csrc, float* __restrict__ cnorm) {
  int i = blockIdx.x * blockDim.x + threadIdx.x;
  if (i >= n) return;
  int d = dst[i];
  int pos = rowptr[d] + atomicAdd(&fill[d], 1);
  int s = src[i];
  csrc[pos] = s;
  cnorm[pos] = dinv[s] * dinv[d];
}

__global__ void k_scatter_nodes(const int* __restrict__ key, int n,
                                const int* __restrict__ rowptr, int* __restrict__ fill,
                                int* __restrict__ out) {
  int i = blockIdx.x * blockDim.x + threadIdx.x;
  if (i >= n) return;
  int d = key[i];
  int pos = rowptr[d] + atomicAdd(&fill[d], 1);
  out[pos] = i;
}

// ---------------- GEMM: Y[r][c] = act(sum_k X[r][k]*W[c][k] + b[c]) ----------------
// 64x64 tile, 4x4 register tile per thread. pad-65 LDS layouts are bank-conflict-free
// for both the cooperative loads and the compute-phase reads.
__global__ __launch_bounds__(256) void k_gemm(const float* __restrict__ X,
                                              const float* __restrict__ W,
                                              const float* __restrict__ bias,
                                              float* __restrict__ Y,
                                              int nrows, int K, int outF, int act) {
  __shared__ float Xt[64][65];  // [row][k]
  __shared__ float Wt[64][65];  // [k][col]
  int row0 = blockIdx.x * 64;
  int col0 = blockIdx.y * 64;
  int tid = threadIdx.x;
  int cg = (tid & 15) * 4;
  int rg = (tid >> 4) * 4;
  float acc[4][4] = {};
  for (int kk = 0; kk < K; kk += 64) {
#pragma unroll
    for (int i = 0; i < 16; ++i) {
      int idx = tid + 256 * i;
      int a = idx >> 6;
      int k = idx & 63;
      int gk = kk + k;
      float xv = 0.f;
      int gr = row0 + a;
      if (gr < nrows && gk < K) xv = X[(size_t)gr * K + gk];
      Xt[a][k] = xv;
      float wv = 0.f;
      int gc = col0 + a;
      if (gc < outF && gk < K) wv = W[(size_t)gc * K + gk];
      Wt[k][a] = wv;
    }
    __syncthreads();
#pragma unroll 8
    for (int k = 0; k < 64; ++k) {
      float w0 = Wt[k][cg + 0], w1 = Wt[k][cg + 1], w2 = Wt[k][cg + 2], w3 = Wt[k][cg + 3];
      float x0 = Xt[rg + 0][k], x1 = Xt[rg + 1][k], x2 = Xt[rg + 2][k], x3 = Xt[rg + 3][k];
      acc[0][0] += x0 * w0; acc[0][1] += x0 * w1; acc[0][2] += x0 * w2; acc[0][3] += x0 * w3;
      acc[1][0] += x1 * w0; acc[1][1] += x1 * w1; acc[1][2] += x1 * w2; acc[1][3] += x1 * w3;
      acc[2][0] += x2 * w0; acc[2][1] += x2 * w1; acc[2][2] += x2 * w2; acc[2][3] += x2 * w3;
      acc[3][0] += x3 * w0; acc[3][1] += x3 * w1; acc[3][2] += x3 * w2; acc[3][3] += x3 * w3;
    }
    __syncthreads();
  }
#pragma unroll
  for (int i = 0; i < 4; ++i) {
    int gr = row0 + rg + i;
    if (gr >= nrows) continue;
#pragma unroll
    for (int j = 0; j < 4; ++j) {
      int gc = col0 + cg + j;
      if (gc >= outF) continue;
      float v = acc[i][j];
      if (bias) v += bias[gc];
      if (act) v = eluf(v);
      Y[(size_t)gr * outF + gc] = v;
    }
  }
}

// ---------------- fine aggregation: wave per dst, fused self-loop+bias+ELU ----------------
__global__ __launch_bounds__(256) void k_agg_fine(int F,
    const int* __restrict__ rowptr, const int* __restrict__ csrc, const float* __restrict__ cnorm,
    const float* __restrict__ h, const float* __restrict__ dinv, const float* __restrict__ bias,
    float* __restrict__ out, int n, int act) {
  int w = blockIdx.x * 4 + (threadIdx.x >> 6);
  if (w >= n) return;
  int lane = threadIdx.x & 63;
  int start = rowptr[w], end = rowptr[w + 1];
  int cpj = F >> 6;  // 1,2,4
  float acc[4] = {0.f, 0.f, 0.f, 0.f};
  for (int e = start; e < end; ++e) {
    int s = csrc[e];
    float nm = cnorm[e];
    const float* hs = h + (size_t)s * F + lane;
#pragma unroll 4
    for (int j = 0; j < cpj; ++j) acc[j] += nm * hs[j * 64];
  }
  float dd = dinv[w]; dd *= dd;
  const float* hw = h + (size_t)w * F + lane;
#pragma unroll 4
  for (int j = 0; j < cpj; ++j) {
    int c = lane + j * 64;
    float v = acc[j] + dd * hw[j * 64] + bias[c];
    if (act) v = eluf(v);
    out[(size_t)w * F + c] = v;
  }
}

// ---------------- coarse aggregation: block per dst (high degree ~470), 4-wave split ----------------
__global__ __launch_bounds__(256) void k_agg_coarse(int F,
    const int* __restrict__ rowptr, const int* __restrict__ csrc, const float* __restrict__ cnorm,
    const float* __restrict__ h, const float* __restrict__ dinv, const float* __restrict__ bias,
    float* __restrict__ out, int act) {
  int d = blockIdx.x;
  int lane = threadIdx.x & 63, wv = threadIdx.x >> 6;
  int start = rowptr[d], end = rowptr[d + 1];
  float acc0 = 0.f, acc1 = 0.f;
  for (int e = start + wv; e < end; e += 4) {
    int s = csrc[e];
    float nm = cnorm[e];
    if (lane < F) acc0 += nm * h[(size_t)s * F + lane];
    if (lane + 64 < F) acc1 += nm * h[(size_t)s * F + lane + 64];
  }
  __shared__ float red[4][128];
  if (lane < F) red[wv][lane] = acc0;
  if (lane + 64 < F) red[wv][lane + 64] = acc1;
  __syncthreads();
  if (wv == 0) {
#pragma unroll 2
    for (int j = 0; j < 2; ++j) {
      int c = lane + j * 64;
      if (c < F) {
        float v = red[0][c] + red[1][c] + red[2][c] + red[3][c];
        float dd = dinv[d] * dinv[d];
        v += dd * h[(size_t)d * F + c] + bias[c];
        if (act) v = eluf(v);
        out[(size_t)d * F + c] = v;
      }
    }
  }
}

// ---------------- instance-norm stats (per-channel over N rows) ----------------
__global__ __launch_bounds__(256) void k_chanstats(const float* __restrict__ x, int n,
                                                   float* __restrict__ s, float* __restrict__ s2) {
  int ch = threadIdx.x;  // 256 channels
  float a = 0.f, b = 0.f;
  for (int r = blockIdx.x; r < n; r += gridDim.x) {
    float v = x[(size_t)r * 256 + ch];
    a += v;
    b += v * v;
  }
  atomicAdd(&s[ch], a);
  atomicAdd(&s2[ch], b);
}

__global__ void k_mufin(const float* __restrict__ s, const float* __restrict__ s2, float n,
                        float* __restrict__ murstd) {
  int ch = threadIdx.x;
  float mu = s[ch] / n;
  float var = s2[ch] / n - mu * mu;
  murstd[ch] = mu;
  murstd[256 + ch] = rsqrtf(var + 1e-5f);
}

// ---------------- fused normalize + cluster mean pool: cx = (cluster_mean(x)-mu)*rstd ----------------
__global__ __launch_bounds__(256) void k_pool(const float* __restrict__ x,
                                              const int* __restrict__ rowptr,
                                              const int* __restrict__ nodes,
                                              const float* __restrict__ murstd,
                                              float* __restrict__ cx) {
  int c = blockIdx.x;
  int ch = threadIdx.x;
  int start = rowptr[c], end = rowptr[c + 1];
  float s = 0.f;
  for (int i = start; i < end; ++i) s += x[(size_t)nodes[i] * 256 + ch];
  int cnt = end - start; if (cnt < 1) cnt = 1;
  float v = s / (float)cnt;
  cx[(size_t)c * 256 + ch] = (v - murstd[ch]) * murstd[256 + ch];
}

// ---------------- o_feat = W_fcO @ g  (614 MB stream, wave per row) ----------------
__global__ __launch_bounds__(256) void k_matvec(const float* __restrict__ W,
                                                const float* __restrict__ g,
                                                float* __restrict__ out, int M, int K) {
  __shared__ __align__(16) float gs[2560];
  for (int i = threadIdx.x; i < K; i += 256) gs[i] = g[i];
  __syncthreads();
  int lane = threadIdx.x & 63, wv = threadIdx.x >> 6;
#pragma unroll
  for (int rr = 0; rr < 4; ++rr) {
    int row = blockIdx.x * 16 + wv * 4 + rr;
    if (row >= M) break;
    const float4* Wr = (const float4*)(W + (size_t)row * K);
    float acc = 0.f;
#pragma unroll
    for (int it = 0; it < 10; ++it) {  // K = 2560 = 10*256
      float4 w4 = Wr[it * 64 + lane];
      float4 g4 = *(const float4*)&gs[it * 256 + lane * 4];
      acc += w4.x * g4.x + w4.y * g4.y + w4.z * g4.z + w4.w * g4.w;
    }
#pragma unroll
    for (int off = 32; off; off >>= 1) acc += __shfl_down(acc, off, 64);
    if (lane == 0) out[row] = acc;
  }
}

// ==================================================================================
extern "C" void kernel_launch(void* const* d_in, const int* in_sizes, int n_in,
                              void* d_out, int out_size, void* d_ws, size_t ws_size,
                              hipStream_t stream) {
  const float* x     = (const float*)d_in[0];
  const float* W_G1  = (const float*)d_in[1];
  const float* b_G1  = (const float*)d_in[2];
  const float* Wf_G1 = (const float*)d_in[3];
  const float* bf_G1 = (const float*)d_in[4];
  const float* W_G2  = (const float*)d_in[5];
  const float* b_G2  = (const float*)d_in[6];
  const float* Wf_G2 = (const float*)d_in[7];
  const float* bf_G2 = (const float*)d_in[8];
  const float* W_L1  = (const float*)d_in[9];
  const float* b_L1  = (const float*)d_in[10];
  const float* Wf_L1 = (const float*)d_in[11];
  const float* bf_L1 = (const float*)d_in[12];
  const float* W_L2  = (const float*)d_in[13];
  const float* b_L2  = (const float*)d_in[14];
  const float* Wf_L2 = (const float*)d_in[15];
  const float* bf_L2 = (const float*)d_in[16];
  const float* W_M1  = (const float*)d_in[17];
  const float* b_M1  = (const float*)d_in[18];
  const float* Wf_M1 = (const float*)d_in[19];
  const float* bf_M1 = (const float*)d_in[20];
  const float* W_O1  = (const float*)d_in[21];
  const float* b_O1  = (const float*)d_in[22];
  const float* W_fcO = (const float*)d_in[23];
  const int* edge    = (const int*)d_in[24];
  const int* cluster = (const int*)d_in[25];
  const int* cedge   = (const int*)d_in[27];

  const int E  = in_sizes[24] / 2;
  const int Ec = in_sizes[27] / 2;

  char* ws = (char*)d_ws;
  size_t off = 0;
  auto alloc = [&](size_t bytes) -> void* {
    void* p = ws + off;
    off = (off + bytes + 255) & ~(size_t)255;
    return p;
  };

  float* bufA = (float*)alloc((size_t)NN * 256 * 4);
  float* bufB = (float*)alloc((size_t)NN * 256 * 4);
  float* bufC = (float*)alloc((size_t)NN * 256 * 4);
  float* cx   = (float*)alloc((size_t)CC * 256 * 4);
  float* zA   = (float*)alloc((size_t)CC * 256 * 4);
  float* zB   = (float*)alloc((size_t)CC * 256 * 4);
  float* dinvF = (float*)alloc((size_t)NN * 4);
  float* dinvC = (float*)alloc((size_t)CC * 4);
  int* rowF  = (int*)alloc((size_t)(NN + 1) * 4);
  int* rowC  = (int*)alloc((size_t)(CC + 1) * 4);
  int* rowCl = (int*)alloc((size_t)(CC + 1) * 4);
  int* csrcF = (int*)alloc((size_t)E * 4);
  float* cnormF = (float*)alloc((size_t)E * 4);
  int* csrcC = (int*)alloc((size_t)Ec * 4);
  float* cnormC = (float*)alloc((size_t)Ec * 4);
  int* cnodes = (int*)alloc((size_t)NN * 4);
  float* murstd = (float*)alloc(512 * 4);
  // ---- contiguous zero region ----
  size_t zoff = off;
  int* degF  = (int*)alloc((size_t)NN * 4);
  int* fillF = (int*)alloc((size_t)NN * 4);
  int* degC  = (int*)alloc((size_t)CC * 4);
  int* fillC = (int*)alloc((size_t)CC * 4);
  int* degCl = (int*)alloc((size_t)CC * 4);
  int* fillCl = (int*)alloc((size_t)CC * 4);
  float* chanS  = (float*)alloc(256 * 4);
  float* chanS2 = (float*)alloc(256 * 4);
  size_t zbytes = off - zoff;

  float* g_out = (float*)d_out;          // [2560] g_feat
  float* o_out = (float*)d_out + 2560;   // [60000] o_feat

  auto cdiv = [](int a, int b) { return (a + b - 1) / b; };

  // zero counters
  k_zero<<<cdiv((int)(zbytes / 16), 256), 256, 0, stream>>>((float4*)(ws + zoff), (int)(zbytes / 16));

  // ---- fine CSR ----
  k_count<<<cdiv(E, 256), 256, 0, stream>>>(edge + E, E, degF);
  k_dinv<<<cdiv(NN, 256), 256, 0, stream>>>(degF, NN, dinvF);
  k_scan<<<1, 1024, 0, stream>>>(degF, NN, rowF);
  k_scatter_edges<<<cdiv(E, 256), 256, 0, stream>>>(edge, edge + E, E, rowF, fillF, dinvF, csrcF, cnormF);

  // ---- coarse CSR ----
  k_count<<<cdiv(Ec, 256), 256, 0, stream>>>(cedge + Ec, Ec, degC);
  k_dinv<<<cdiv(CC, 256), 256, 0, stream>>>(degC, CC, dinvC);
  k_scan<<<1, 1024, 0, stream>>>(degC, CC, rowC);
  k_scatter_edges<<<cdiv(Ec, 256), 256, 0, stream>>>(cedge, cedge + Ec, Ec, rowC, fillC, dinvC, csrcC, cnormC);

  // ---- cluster CSR (counting sort of nodes by cluster) ----
  k_count<<<cdiv(NN, 256), 256, 0, stream>>>(cluster, NN, degCl);
  k_scan<<<1, 1024, 0, stream>>>(degCl, CC, rowCl);
  k_scatter_nodes<<<cdiv(NN, 256), 256, 0, stream>>>(cluster, NN, rowCl, fillCl, cnodes);

  // ---- fine pipeline ----
  // h1 = x @ W_G1.T  [N,64]
  k_gemm<<<dim3(cdiv(NN, 64), 1), 256, 0, stream>>>(x, W_G1, nullptr, bufA, NN, 128, 64, 0);
  // x1 = elu(agg(h1) + b)  [N,64]
  k_agg_fine<<<NN / 4, 256, 0, stream>>>(64, rowF, csrcF, cnormF, bufA, dinvF, b_G1, bufC, NN, 1);
  // x2 = elu(x1 @ Wf_G1.T + bf)  [N,128]
  k_gemm<<<dim3(cdiv(NN, 64), 2), 256, 0, stream>>>(bufC, Wf_G1, bf_G1, bufA, NN, 64, 128, 1);
  // h2 = x2 @ W_G2.T  [N,256]
  k_gemm<<<dim3(cdiv(NN, 64), 4), 256, 0, stream>>>(bufA, W_G2, nullptr, bufB, NN, 128, 256, 0);
  // x3 = elu(agg(h2) + b)  [N,256]
  k_agg_fine<<<NN / 4, 256, 0, stream>>>(256, rowF, csrcF, cnormF, bufB, dinvF, b_G2, bufC, NN, 1);
  // x4 = elu(x3 @ Wf_G2.T + bf)  [N,256]
  k_gemm<<<dim3(cdiv(NN, 64), 4), 256, 0, stream>>>(bufC, Wf_G2, bf_G2, bufA, NN, 256, 256, 1);

  // ---- instance norm stats + fused pool ----
  k_chanstats<<<256, 256, 0, stream>>>(bufA, NN, chanS, chanS2);
  k_mufin<<<1, 256, 0, stream>>>(chanS, chanS2, (float)NN, murstd);
  k_pool<<<CC, 256, 0, stream>>>(bufA, rowCl, cnodes, murstd, cx);

  // ---- coarse pipeline ----
  k_gemm<<<dim3(cdiv(CC, 64), 2), 256, 0, stream>>>(cx, W_L1, nullptr, zA, CC, 256, 128, 0);
  k_agg_coarse<<<CC, 256, 0, stream>>>(128, rowC, csrcC, cnormC, zA, dinvC, b_L1, zB, 1);
  k_gemm<<<dim3(cdiv(CC, 64), 2), 256, 0, stream>>>(zB, Wf_L1, bf_L1, zA, CC, 128, 96, 1);
  k_gemm<<<dim3(cdiv(CC, 64), 1), 256, 0, stream>>>(zA, W_L2, nullptr, zB, CC, 96, 64, 0);
  k_agg_coarse<<<CC, 256, 0, stream>>>(64, rowC, csrcC, cnormC, zB, dinvC, b_L2, zA, 1);
  k_gemm<<<dim3(cdiv(CC, 64), 1), 256, 0, stream>>>(zA, Wf_L2, bf_L2, zB, CC, 64, 32, 1);
  k_gemm<<<dim3(cdiv(CC, 64), 1), 256, 0, stream>>>(zB, W_M1, nullptr, zA, CC, 32, 16, 0);
  k_agg_coarse<<<CC, 256, 0, stream>>>(16, rowC, csrcC, cnormC, zA, dinvC, b_M1, zB, 1);
  k_gemm<<<dim3(cdiv(CC, 64), 1), 256, 0, stream>>>(zB, Wf_M1, bf_M1, zA, CC, 16, 8, 1);
  k_gemm<<<dim3(cdiv(CC, 64), 1), 256, 0, stream>>>(zA, W_O1, nullptr, zB, CC, 8, 5, 0);
  // g_feat = agg(h_O1) + b_O1 (no ELU) -> d_out[0:2560]
  k_agg_coarse<<<CC, 256, 0, stream>>>(5, rowC, csrcC, cnormC, zB, dinvC, b_O1, g_out, 0);

  // ---- o_feat = W_fcO @ g_feat ----
  k_matvec<<<cdiv(3 * NN, 16), 256, 0, stream>>>(W_fcO, g_out, o_out, 3 * NN, 2560);
}

// Round 2
// 860.632 us; speedup vs baseline: 1.1991x; 1.1991x over previous
//
#include <hip/hip_runtime.h>
#include <math.h>

#define NN 20000
#define CC 512

__device__ __forceinline__ float eluf(float x) { return x > 0.f ? x : expm1f(x); }

// ---------------- zero ----------------
__global__ void k_zero(float4* __restrict__ p, int n4) {
  int i = blockIdx.x * blockDim.x + threadIdx.x;
  if (i < n4) p[i] = make_float4(0.f, 0.f, 0.f, 0.f);
}

// ---------------- CSR build ----------------
__global__ void k_count(const int* __restrict__ key, int n, int* __restrict__ cnt) {
  int i = blockIdx.x * blockDim.x + threadIdx.x;
  if (i < n) atomicAdd(&cnt[key[i]], 1);
}

__global__ void k_dinv(const int* __restrict__ deg, int n, float* __restrict__ dinv) {
  int i = blockIdx.x * blockDim.x + threadIdx.x;
  if (i < n) dinv[i] = rsqrtf((float)(deg[i] + 1));  // +1 self-loop
}

__global__ __launch_bounds__(1024) void k_scan(const int* __restrict__ counts, int n,
                                               int* __restrict__ rowptr) {
  __shared__ int part[1024];
  int tid = threadIdx.x;
  int chunk = (n + 1023) >> 10;
  int beg = tid * chunk;
  int fin = beg + chunk; if (fin > n) fin = n;
  int s = 0;
  for (int i = beg; i < fin; ++i) s += counts[i];
  part[tid] = s;
  __syncthreads();
  for (int off = 1; off < 1024; off <<= 1) {
    int v = (tid >= off) ? part[tid - off] : 0;
    __syncthreads();
    part[tid] += v;
    __syncthreads();
  }
  int base = (tid == 0) ? 0 : part[tid - 1];
  for (int i = beg; i < fin; ++i) { rowptr[i] = base; base += counts[i]; }
  if (tid == 1023) rowptr[n] = part[1023];
}

__global__ void k_scatter_edges(const int* __restrict__ src, const int* __restrict__ dst, int n,
                                const int* __restrict__ rowptr, int* __restrict__ fill,
                                const float* __restrict__ dinv,
                                int* __restrict__ csrc, float* __restrict__ cnorm) {
  int i = blockIdx.x * blockDim.x + threadIdx.x;
  if (i >= n) return;
  int d = dst[i];
  int pos = rowptr[d] + atomicAdd(&fill[d], 1);
  int s = src[i];
  csrc[pos] = s;
  cnorm[pos] = dinv[s] * dinv[d];
}

__global__ void k_scatter_nodes(const int* __restrict__ key, int n,
                                const int* __restrict__ rowptr, int* __restrict__ fill,
                                int* __restrict__ out) {
  int i = blockIdx.x * blockDim.x + threadIdx.x;
  if (i >= n) return;
  int d = key[i];
  int pos = rowptr[d] + atomicAdd(&fill[d], 1);
  out[pos] = i;
}

// ---------------- small GEMM (coarse stages): 64x64 tile ----------------
__global__ __launch_bounds__(256) void k_gemm(const float* __restrict__ X,
                                              const float* __restrict__ W,
                                              const float* __restrict__ bias,
                                              float* __restrict__ Y,
                                              int nrows, int K, int outF, int act) {
  __shared__ float Xt[64][65];
  __shared__ float Wt[64][65];
  int row0 = blockIdx.x * 64;
  int col0 = blockIdx.y * 64;
  int tid = threadIdx.x;
  int cg = (tid & 15) * 4;
  int rg = (tid >> 4) * 4;
  float acc[4][4] = {};
  for (int kk = 0; kk < K; kk += 64) {
#pragma unroll
    for (int i = 0; i < 16; ++i) {
      int idx = tid + 256 * i;
      int a = idx >> 6;
      int k = idx & 63;
      int gk = kk + k;
      float xv = 0.f;
      int gr = row0 + a;
      if (gr < nrows && gk < K) xv = X[(size_t)gr * K + gk];
      Xt[a][k] = xv;
      float wv = 0.f;
      int gc = col0 + a;
      if (gc < outF && gk < K) wv = W[(size_t)gc * K + gk];
      Wt[k][a] = wv;
    }
    __syncthreads();
#pragma unroll 8
    for (int k = 0; k < 64; ++k) {
      float w0 = Wt[k][cg + 0], w1 = Wt[k][cg + 1], w2 = Wt[k][cg + 2], w3 = Wt[k][cg + 3];
      float x0 = Xt[rg + 0][k], x1 = Xt[rg + 1][k], x2 = Xt[rg + 2][k], x3 = Xt[rg + 3][k];
      acc[0][0] += x0 * w0; acc[0][1] += x0 * w1; acc[0][2] += x0 * w2; acc[0][3] += x0 * w3;
      acc[1][0] += x1 * w0; acc[1][1] += x1 * w1; acc[1][2] += x1 * w2; acc[1][3] += x1 * w3;
      acc[2][0] += x2 * w0; acc[2][1] += x2 * w1; acc[2][2] += x2 * w2; acc[2][3] += x2 * w3;
      acc[3][0] += x3 * w0; acc[3][1] += x3 * w1; acc[3][2] += x3 * w2; acc[3][3] += x3 * w3;
    }
    __syncthreads();
  }
#pragma unroll
  for (int i = 0; i < 4; ++i) {
    int gr = row0 + rg + i;
    if (gr >= nrows) continue;
#pragma unroll
    for (int j = 0; j < 4; ++j) {
      int gc = col0 + cg + j;
      if (gc >= outF) continue;
      float v = acc[i][j];
      if (bias) v += bias[gc];
      if (act) v = eluf(v);
      Y[(size_t)gr * outF + gc] = v;
    }
  }
}

// ---------------- big GEMM (fine stages): 128x64 tile, BK=32, 8x4/thread ----------------
// Both LDS tiles stored [k][.]; strides 132/68 keep float4 rows 16B-aligned.
// Compute-phase reads: conflict-free (Xt) / 2-way (Wt, free). Write-phase 4-way conflict
// is ~7% of the 2048-cyc compute phase -> negligible.
__global__ __launch_bounds__(256) void k_gemm2(const float* __restrict__ X,
                                               const float* __restrict__ W,
                                               const float* __restrict__ bias,
                                               float* __restrict__ Y,
                                               int nrows, int K, int outF, int act) {
  __shared__ float Xt[32][132];
  __shared__ float Wt[32][68];
  int row0 = blockIdx.x * 128;
  int col0 = blockIdx.y * 64;
  int tid = threadIdx.x;
  int tc = (tid & 15) * 4;
  int tr = (tid >> 4) * 8;
  float acc[8][4] = {};
  for (int kk = 0; kk < K; kk += 32) {
#pragma unroll
    for (int i = 0; i < 16; ++i) {
      int idx = tid + 256 * i;
      int k = idx & 31, r = idx >> 5;
      int gr = row0 + r, gk = kk + k;
      Xt[k][r] = (gr < nrows && gk < K) ? X[(size_t)gr * K + gk] : 0.f;
    }
#pragma unroll
    for (int i = 0; i < 8; ++i) {
      int idx = tid + 256 * i;
      int k = idx & 31, c = idx >> 5;
      int gc = col0 + c, gk = kk + k;
      Wt[k][c] = (gc < outF && gk < K) ? W[(size_t)gc * K + gk] : 0.f;
    }
    __syncthreads();
#pragma unroll 8
    for (int k = 0; k < 32; ++k) {
      float4 w = *(const float4*)&Wt[k][tc];
      float4 xa = *(const float4*)&Xt[k][tr];
      float4 xb = *(const float4*)&Xt[k][tr + 4];
      float xs[8] = {xa.x, xa.y, xa.z, xa.w, xb.x, xb.y, xb.z, xb.w};
      float ws4[4] = {w.x, w.y, w.z, w.w};
#pragma unroll
      for (int i = 0; i < 8; ++i)
#pragma unroll
        for (int j = 0; j < 4; ++j) acc[i][j] += xs[i] * ws4[j];
    }
    __syncthreads();
  }
#pragma unroll
  for (int i = 0; i < 8; ++i) {
    int gr = row0 + tr + i;
    if (gr >= nrows) continue;
    int gc = col0 + tc;
    float4 v;
    v.x = acc[i][0]; v.y = acc[i][1]; v.z = acc[i][2]; v.w = acc[i][3];
    if (bias) { v.x += bias[gc]; v.y += bias[gc + 1]; v.z += bias[gc + 2]; v.w += bias[gc + 3]; }
    if (act) { v.x = eluf(v.x); v.y = eluf(v.y); v.z = eluf(v.z); v.w = eluf(v.w); }
    if (gc + 3 < outF) {
      *(float4*)&Y[(size_t)gr * outF + gc] = v;
    } else {
      float vs[4] = {v.x, v.y, v.z, v.w};
      for (int j = 0; j < 4; ++j)
        if (gc + j < outF) Y[(size_t)gr * outF + gc + j] = vs[j];
    }
  }
}

// ---------------- fine aggregation F=256: wave/dst, float4/lane, 4x unrolled ----------------
__global__ __launch_bounds__(256) void k_agg_fine256(
    const int* __restrict__ rowptr, const int* __restrict__ csrc, const float* __restrict__ cnorm,
    const float4* __restrict__ h4, const float* __restrict__ dinv, const float4* __restrict__ bias4,
    float4* __restrict__ out4, int n) {
  int w = blockIdx.x * 4 + (threadIdx.x >> 6);
  if (w >= n) return;
  int lane = threadIdx.x & 63;
  int start = rowptr[w], end = rowptr[w + 1];
  float4 acc = make_float4(0.f, 0.f, 0.f, 0.f);
  int e = start;
  for (; e + 3 < end; e += 4) {
    int s0 = csrc[e], s1 = csrc[e + 1], s2 = csrc[e + 2], s3 = csrc[e + 3];
    float n0 = cnorm[e], n1 = cnorm[e + 1], n2 = cnorm[e + 2], n3 = cnorm[e + 3];
    float4 v0 = h4[(size_t)s0 * 64 + lane];
    float4 v1 = h4[(size_t)s1 * 64 + lane];
    float4 v2 = h4[(size_t)s2 * 64 + lane];
    float4 v3 = h4[(size_t)s3 * 64 + lane];
    acc.x += n0 * v0.x + n1 * v1.x + n2 * v2.x + n3 * v3.x;
    acc.y += n0 * v0.y + n1 * v1.y + n2 * v2.y + n3 * v3.y;
    acc.z += n0 * v0.z + n1 * v1.z + n2 * v2.z + n3 * v3.z;
    acc.w += n0 * v0.w + n1 * v1.w + n2 * v2.w + n3 * v3.w;
  }
  for (; e < end; ++e) {
    int s = csrc[e];
    float nm = cnorm[e];
    float4 v = h4[(size_t)s * 64 + lane];
    acc.x += nm * v.x; acc.y += nm * v.y; acc.z += nm * v.z; acc.w += nm * v.w;
  }
  float dd = dinv[w]; dd *= dd;
  float4 hw = h4[(size_t)w * 64 + lane];
  float4 b = bias4[lane];
  float4 o;
  o.x = eluf(acc.x + dd * hw.x + b.x);
  o.y = eluf(acc.y + dd * hw.y + b.y);
  o.z = eluf(acc.z + dd * hw.z + b.z);
  o.w = eluf(acc.w + dd * hw.w + b.w);
  out4[(size_t)w * 64 + lane] = o;
}

// ---------------- fine aggregation F=64: wave/dst, scalar/lane, 4x unrolled ----------------
__global__ __launch_bounds__(256) void k_agg_fine64(
    const int* __restrict__ rowptr, const int* __restrict__ csrc, const float* __restrict__ cnorm,
    const float* __restrict__ h, const float* __restrict__ dinv, const float* __restrict__ bias,
    float* __restrict__ out, int n) {
  int w = blockIdx.x * 4 + (threadIdx.x >> 6);
  if (w >= n) return;
  int lane = threadIdx.x & 63;
  int start = rowptr[w], end = rowptr[w + 1];
  float acc = 0.f;
  int e = start;
  for (; e + 3 < end; e += 4) {
    int s0 = csrc[e], s1 = csrc[e + 1], s2 = csrc[e + 2], s3 = csrc[e + 3];
    float n0 = cnorm[e], n1 = cnorm[e + 1], n2 = cnorm[e + 2], n3 = cnorm[e + 3];
    float v0 = h[(size_t)s0 * 64 + lane];
    float v1 = h[(size_t)s1 * 64 + lane];
    float v2 = h[(size_t)s2 * 64 + lane];
    float v3 = h[(size_t)s3 * 64 + lane];
    acc += n0 * v0 + n1 * v1 + n2 * v2 + n3 * v3;
  }
  for (; e < end; ++e) acc += cnorm[e] * h[(size_t)csrc[e] * 64 + lane];
  float dd = dinv[w]; dd *= dd;
  out[(size_t)w * 64 + lane] = eluf(acc + dd * h[(size_t)w * 64 + lane] + bias[lane]);
}

// ---------------- coarse aggregation (block/dst) + optional fused FC ----------------
__global__ __launch_bounds__(256) void k_agg_coarse(int F,
    const int* __restrict__ rowptr, const int* __restrict__ csrc, const float* __restrict__ cnorm,
    const float* __restrict__ h, const float* __restrict__ dinv, const float* __restrict__ bias,
    float* __restrict__ out, int act) {
  int d = blockIdx.x;
  int lane = threadIdx.x & 63, wv = threadIdx.x >> 6;
  int start = rowptr[d], end = rowptr[d + 1];
  float acc0 = 0.f, acc1 = 0.f;
  for (int e = start + wv; e < end; e += 4) {
    int s = csrc[e];
    float nm = cnorm[e];
    if (lane < F) acc0 += nm * h[(size_t)s * F + lane];
    if (lane + 64 < F) acc1 += nm * h[(size_t)s * F + lane + 64];
  }
  __shared__ float red[4][128];
  if (lane < F) red[wv][lane] = acc0;
  if (lane + 64 < F) red[wv][lane + 64] = acc1;
  __syncthreads();
  if (wv == 0) {
#pragma unroll 2
    for (int j = 0; j < 2; ++j) {
      int c = lane + j * 64;
      if (c < F) {
        float v = red[0][c] + red[1][c] + red[2][c] + red[3][c];
        float dd = dinv[d] * dinv[d];
        v += dd * h[(size_t)d * F + c] + bias[c];
        if (act) v = eluf(v);
        out[(size_t)d * F + c] = v;
      }
    }
  }
}

__global__ __launch_bounds__(256) void k_agg_coarse_fc(int F,
    const int* __restrict__ rowptr, const int* __restrict__ csrc, const float* __restrict__ cnorm,
    const float* __restrict__ h, const float* __restrict__ dinv, const float* __restrict__ bias,
    const float* __restrict__ Wf, const float* __restrict__ bf, int outF2,
    float* __restrict__ out) {
  int d = blockIdx.x;
  int lane = threadIdx.x & 63, wv = threadIdx.x >> 6;
  int start = rowptr[d], end = rowptr[d + 1];
  float acc0 = 0.f, acc1 = 0.f;
  for (int e = start + wv; e < end; e += 4) {
    int s = csrc[e];
    float nm = cnorm[e];
    if (lane < F) acc0 += nm * h[(size_t)s * F + lane];
    if (lane + 64 < F) acc1 += nm * h[(size_t)s * F + lane + 64];
  }
  __shared__ float red[4][128];
  __shared__ __align__(16) float a_sh[128];
  if (lane < F) red[wv][lane] = acc0;
  if (lane + 64 < F) red[wv][lane + 64] = acc1;
  __syncthreads();
  if (wv == 0) {
#pragma unroll 2
    for (int j = 0; j < 2; ++j) {
      int c = lane + j * 64;
      if (c < F) {
        float v = red[0][c] + red[1][c] + red[2][c] + red[3][c];
        float dd = dinv[d] * dinv[d];
        a_sh[c] = eluf(v + dd * h[(size_t)d * F + c] + bias[c]);
      }
    }
  }
  __syncthreads();
  // FC: out[d][j] = elu(a . Wf[j] + bf[j])
  int j = threadIdx.x;
  if (j < outF2) {
    const float4* wr = (const float4*)(Wf + (size_t)j * F);
    const float4* ar = (const float4*)a_sh;
    float s = bf[j];
    for (int c = 0; c < (F >> 2); ++c) {
      float4 wv4 = wr[c];
      float4 av = ar[c];
      s += wv4.x * av.x + wv4.y * av.y + wv4.z * av.z + wv4.w * av.w;
    }
    out[(size_t)d * outF2 + j] = eluf(s);
  }
}

// ---------------- instance-norm stats ----------------
__global__ __launch_bounds__(256) void k_chanstats(const float* __restrict__ x, int n,
                                                   float* __restrict__ s, float* __restrict__ s2) {
  int ch = threadIdx.x;
  float a = 0.f, b = 0.f;
  for (int r = blockIdx.x; r < n; r += gridDim.x) {
    float v = x[(size_t)r * 256 + ch];
    a += v;
    b += v * v;
  }
  atomicAdd(&s[ch], a);
  atomicAdd(&s2[ch], b);
}

__global__ void k_mufin(const float* __restrict__ s, const float* __restrict__ s2, float n,
                        float* __restrict__ murstd) {
  int ch = threadIdx.x;
  float mu = s[ch] / n;
  float var = s2[ch] / n - mu * mu;
  murstd[ch] = mu;
  murstd[256 + ch] = rsqrtf(var + 1e-5f);
}

// ---------------- fused normalize + cluster mean pool ----------------
__global__ __launch_bounds__(256) void k_pool(const float* __restrict__ x,
                                              const int* __restrict__ rowptr,
                                              const int* __restrict__ nodes,
                                              const float* __restrict__ murstd,
                                              float* __restrict__ cx) {
  int c = blockIdx.x;
  int ch = threadIdx.x;
  int start = rowptr[c], end = rowptr[c + 1];
  float s = 0.f;
  for (int i = start; i < end; ++i) s += x[(size_t)nodes[i] * 256 + ch];
  int cnt = end - start; if (cnt < 1) cnt = 1;
  float v = s / (float)cnt;
  cx[(size_t)c * 256 + ch] = (v - murstd[ch]) * murstd[256 + ch];
}

// ---------------- o_feat = W_fcO @ g ----------------
__global__ __launch_bounds__(256) void k_matvec(const float* __restrict__ W,
                                                const float* __restrict__ g,
                                                float* __restrict__ out, int M, int K) {
  __shared__ __align__(16) float gs[2560];
  for (int i = threadIdx.x; i < K; i += 256) gs[i] = g[i];
  __syncthreads();
  int lane = threadIdx.x & 63, wv = threadIdx.x >> 6;
#pragma unroll
  for (int rr = 0; rr < 4; ++rr) {
    int row = blockIdx.x * 16 + wv * 4 + rr;
    if (row >= M) break;
    const float4* Wr = (const float4*)(W + (size_t)row * K);
    float acc = 0.f;
#pragma unroll
    for (int it = 0; it < 10; ++it) {
      float4 w4 = Wr[it * 64 + lane];
      float4 g4 = *(const float4*)&gs[it * 256 + lane * 4];
      acc += w4.x * g4.x + w4.y * g4.y + w4.z * g4.z + w4.w * g4.w;
    }
#pragma unroll
    for (int off = 32; off; off >>= 1) acc += __shfl_down(acc, off, 64);
    if (lane == 0) out[row] = acc;
  }
}

// ==================================================================================
extern "C" void kernel_launch(void* const* d_in, const int* in_sizes, int n_in,
                              void* d_out, int out_size, void* d_ws, size_t ws_size,
                              hipStream_t stream) {
  const float* x     = (const float*)d_in[0];
  const float* W_G1  = (const float*)d_in[1];
  const float* b_G1  = (const float*)d_in[2];
  const float* Wf_G1 = (const float*)d_in[3];
  const float* bf_G1 = (const float*)d_in[4];
  const float* W_G2  = (const float*)d_in[5];
  const float* b_G2  = (const float*)d_in[6];
  const float* Wf_G2 = (const float*)d_in[7];
  const float* bf_G2 = (const float*)d_in[8];
  const float* W_L1  = (const float*)d_in[9];
  const float* b_L1  = (const float*)d_in[10];
  const float* Wf_L1 = (const float*)d_in[11];
  const float* bf_L1 = (const float*)d_in[12];
  const float* W_L2  = (const float*)d_in[13];
  const float* b_L2  = (const float*)d_in[14];
  const float* Wf_L2 = (const float*)d_in[15];
  const float* bf_L2 = (const float*)d_in[16];
  const float* W_M1  = (const float*)d_in[17];
  const float* b_M1  = (const float*)d_in[18];
  const float* Wf_M1 = (const float*)d_in[19];
  const float* bf_M1 = (const float*)d_in[20];
  const float* W_O1  = (const float*)d_in[21];
  const float* b_O1  = (const float*)d_in[22];
  const float* W_fcO = (const float*)d_in[23];
  const int* edge    = (const int*)d_in[24];
  const int* cluster = (const int*)d_in[25];
  const int* cedge   = (const int*)d_in[27];

  const int E  = in_sizes[24] / 2;
  const int Ec = in_sizes[27] / 2;

  char* ws = (char*)d_ws;
  size_t off = 0;
  auto alloc = [&](size_t bytes) -> void* {
    void* p = ws + off;
    off = (off + bytes + 255) & ~(size_t)255;
    return p;
  };

  float* bufA = (float*)alloc((size_t)NN * 256 * 4);
  float* bufB = (float*)alloc((size_t)NN * 256 * 4);
  float* bufC = (float*)alloc((size_t)NN * 256 * 4);
  float* cx   = (float*)alloc((size_t)CC * 256 * 4);
  float* zA   = (float*)alloc((size_t)CC * 256 * 4);
  float* zB   = (float*)alloc((size_t)CC * 256 * 4);
  float* dinvF = (float*)alloc((size_t)NN * 4);
  float* dinvC = (float*)alloc((size_t)CC * 4);
  int* rowF  = (int*)alloc((size_t)(NN + 1) * 4);
  int* rowC  = (int*)alloc((size_t)(CC + 1) * 4);
  int* rowCl = (int*)alloc((size_t)(CC + 1) * 4);
  int* csrcF = (int*)alloc((size_t)E * 4);
  float* cnormF = (float*)alloc((size_t)E * 4);
  int* csrcC = (int*)alloc((size_t)Ec * 4);
  float* cnormC = (float*)alloc((size_t)Ec * 4);
  int* cnodes = (int*)alloc((size_t)NN * 4);
  float* murstd = (float*)alloc(512 * 4);
  // ---- contiguous zero region ----
  size_t zoff = off;
  int* degF  = (int*)alloc((size_t)NN * 4);
  int* fillF = (int*)alloc((size_t)NN * 4);
  int* degC  = (int*)alloc((size_t)CC * 4);
  int* fillC = (int*)alloc((size_t)CC * 4);
  int* degCl = (int*)alloc((size_t)CC * 4);
  int* fillCl = (int*)alloc((size_t)CC * 4);
  float* chanS  = (float*)alloc(256 * 4);
  float* chanS2 = (float*)alloc(256 * 4);
  size_t zbytes = off - zoff;

  float* g_out = (float*)d_out;          // [2560] g_feat
  float* o_out = (float*)d_out + 2560;   // [60000] o_feat

  auto cdiv = [](int a, int b) { return (a + b - 1) / b; };

  k_zero<<<cdiv((int)(zbytes / 16), 256), 256, 0, stream>>>((float4*)(ws + zoff), (int)(zbytes / 16));

  // ---- fine CSR ----
  k_count<<<cdiv(E, 256), 256, 0, stream>>>(edge + E, E, degF);
  k_dinv<<<cdiv(NN, 256), 256, 0, stream>>>(degF, NN, dinvF);
  k_scan<<<1, 1024, 0, stream>>>(degF, NN, rowF);
  k_scatter_edges<<<cdiv(E, 256), 256, 0, stream>>>(edge, edge + E, E, rowF, fillF, dinvF, csrcF, cnormF);

  // ---- coarse CSR ----
  k_count<<<cdiv(Ec, 256), 256, 0, stream>>>(cedge + Ec, Ec, degC);
  k_dinv<<<cdiv(CC, 256), 256, 0, stream>>>(degC, CC, dinvC);
  k_scan<<<1, 1024, 0, stream>>>(degC, CC, rowC);
  k_scatter_edges<<<cdiv(Ec, 256), 256, 0, stream>>>(cedge, cedge + Ec, Ec, rowC, fillC, dinvC, csrcC, cnormC);

  // ---- cluster CSR ----
  k_count<<<cdiv(NN, 256), 256, 0, stream>>>(cluster, NN, degCl);
  k_scan<<<1, 1024, 0, stream>>>(degCl, CC, rowCl);
  k_scatter_nodes<<<cdiv(NN, 256), 256, 0, stream>>>(cluster, NN, rowCl, fillCl, cnodes);

  // ---- fine pipeline ----
  k_gemm2<<<dim3(cdiv(NN, 128), 1), 256, 0, stream>>>(x, W_G1, nullptr, bufA, NN, 128, 64, 0);
  k_agg_fine64<<<NN / 4, 256, 0, stream>>>(rowF, csrcF, cnormF, bufA, dinvF, b_G1, bufC, NN);
  k_gemm2<<<dim3(cdiv(NN, 128), 2), 256, 0, stream>>>(bufC, Wf_G1, bf_G1, bufA, NN, 64, 128, 1);
  k_gemm2<<<dim3(cdiv(NN, 128), 4), 256, 0, stream>>>(bufA, W_G2, nullptr, bufB, NN, 128, 256, 0);
  k_agg_fine256<<<NN / 4, 256, 0, stream>>>(rowF, csrcF, cnormF, (const float4*)bufB, dinvF,
                                            (const float4*)b_G2, (float4*)bufC, NN);
  k_gemm2<<<dim3(cdiv(NN, 128), 4), 256, 0, stream>>>(bufC, Wf_G2, bf_G2, bufA, NN, 256, 256, 1);

  // ---- instance norm stats + fused pool ----
  k_chanstats<<<256, 256, 0, stream>>>(bufA, NN, chanS, chanS2);
  k_mufin<<<1, 256, 0, stream>>>(chanS, chanS2, (float)NN, murstd);
  k_pool<<<CC, 256, 0, stream>>>(bufA, rowCl, cnodes, murstd, cx);

  // ---- coarse pipeline (GCN-gemm, then fused agg+FC) ----
  k_gemm<<<dim3(cdiv(CC, 64), 2), 256, 0, stream>>>(cx, W_L1, nullptr, zA, CC, 256, 128, 0);
  k_agg_coarse_fc<<<CC, 256, 0, stream>>>(128, rowC, csrcC, cnormC, zA, dinvC, b_L1,
                                          Wf_L1, bf_L1, 96, zB);
  k_gemm<<<dim3(cdiv(CC, 64), 1), 256, 0, stream>>>(zB, W_L2, nullptr, zA, CC, 96, 64, 0);
  k_agg_coarse_fc<<<CC, 256, 0, stream>>>(64, rowC, csrcC, cnormC, zA, dinvC, b_L2,
                                          Wf_L2, bf_L2, 32, zB);
  k_gemm<<<dim3(cdiv(CC, 64), 1), 256, 0, stream>>>(zB, W_M1, nullptr, zA, CC, 32, 16, 0);
  k_agg_coarse_fc<<<CC, 256, 0, stream>>>(16, rowC, csrcC, cnormC, zA, dinvC, b_M1,
                                          Wf_M1, bf_M1, 8, zB);
  k_gemm<<<dim3(cdiv(CC, 64), 1), 256, 0, stream>>>(zB, W_O1, nullptr, zA, CC, 8, 5, 0);
  k_agg_coarse<<<CC, 256, 0, stream>>>(5, rowC, csrcC, cnormC, zA, dinvC, b_O1, g_out, 0);

  // ---- o_feat = W_fcO @ g_feat ----
  k_matvec<<<cdiv(3 * NN, 16), 256, 0, stream>>>(W_fcO, g_out, o_out, 3 * NN, 2560);
}

// Round 3
// 786.049 us; speedup vs baseline: 1.3129x; 1.0949x over previous
//
#include <hip/hip_runtime.h>
#include <math.h>

#define NN 20000
#define CC 512

__device__ __forceinline__ float eluf(float x) { return x > 0.f ? x : __expf(x) - 1.f; }

// ---------------- zero ----------------
__global__ void k_zero(float4* __restrict__ p, int n4) {
  int i = blockIdx.x * blockDim.x + threadIdx.x;
  if (i < n4) p[i] = make_float4(0.f, 0.f, 0.f, 0.f);
}

// ---------------- fused CSR counting (fine dst, coarse dst, cluster) ----------------
__global__ void k_count3(const int* __restrict__ dstF, int nF, int* __restrict__ cF,
                         const int* __restrict__ dstC, int nC, int* __restrict__ cC,
                         const int* __restrict__ clus, int nK, int* __restrict__ cK) {
  int i = blockIdx.x * blockDim.x + threadIdx.x;
  if (i < nF) { atomicAdd(&cF[dstF[i]], 1); return; }
  i -= nF;
  if (i < nC) { atomicAdd(&cC[dstC[i]], 1); return; }
  i -= nC;
  if (i < nK) atomicAdd(&cK[clus[i]], 1);
}

// ---------------- 3-array scan (block per array) + optional dinv ----------------
__global__ __launch_bounds__(1024) void k_scan3(
    const int* __restrict__ c0, int n0, int* __restrict__ r0, float* __restrict__ d0,
    const int* __restrict__ c1, int n1, int* __restrict__ r1, float* __restrict__ d1,
    const int* __restrict__ c2, int n2, int* __restrict__ r2) {
  const int* counts; int n; int* rowptr; float* dinv;
  if (blockIdx.x == 0) { counts = c0; n = n0; rowptr = r0; dinv = d0; }
  else if (blockIdx.x == 1) { counts = c1; n = n1; rowptr = r1; dinv = d1; }
  else { counts = c2; n = n2; rowptr = r2; dinv = nullptr; }
  __shared__ int part[1024];
  int tid = threadIdx.x;
  int chunk = (n + 1023) >> 10;
  int beg = tid * chunk;
  int fin = beg + chunk; if (fin > n) fin = n;
  int s = 0;
  for (int i = beg; i < fin; ++i) {
    int c = counts[i];
    s += c;
    if (dinv) dinv[i] = rsqrtf((float)(c + 1));  // +1 self-loop
  }
  part[tid] = s;
  __syncthreads();
  for (int off = 1; off < 1024; off <<= 1) {
    int v = (tid >= off) ? part[tid - off] : 0;
    __syncthreads();
    part[tid] += v;
    __syncthreads();
  }
  int base = (tid == 0) ? 0 : part[tid - 1];
  for (int i = beg; i < fin; ++i) { rowptr[i] = base; base += counts[i]; }
  if (tid == 1023) rowptr[n] = part[1023];
}

// ---------------- fused scatter (fine edges, coarse edges, cluster nodes) ----------------
__global__ void k_scatter3(
    const int* __restrict__ edgeF, int EF, const int* __restrict__ rowF, int* __restrict__ fillF,
    const float* __restrict__ dinvF, int* __restrict__ csrcF, float* __restrict__ cnormF,
    const int* __restrict__ edgeC, int EC, const int* __restrict__ rowC, int* __restrict__ fillC,
    const float* __restrict__ dinvC, int* __restrict__ csrcC, float* __restrict__ cnormC,
    const int* __restrict__ clus, int NK, const int* __restrict__ rowK, int* __restrict__ fillK,
    int* __restrict__ cnodes) {
  int i = blockIdx.x * blockDim.x + threadIdx.x;
  if (i < EF) {
    int d = edgeF[EF + i];
    int pos = rowF[d] + atomicAdd(&fillF[d], 1);
    int s = edgeF[i];
    csrcF[pos] = s;
    cnormF[pos] = dinvF[s] * dinvF[d];
    return;
  }
  i -= EF;
  if (i < EC) {
    int d = edgeC[EC + i];
    int pos = rowC[d] + atomicAdd(&fillC[d], 1);
    int s = edgeC[i];
    csrcC[pos] = s;
    cnormC[pos] = dinvC[s] * dinvC[d];
    return;
  }
  i -= EC;
  if (i < NK) {
    int d = clus[i];
    int pos = rowK[d] + atomicAdd(&fillK[d], 1);
    cnodes[pos] = i;
  }
}

// ---------------- small GEMM (coarse stages): 64x64 tile ----------------
__global__ __launch_bounds__(256) void k_gemm(const float* __restrict__ X,
                                              const float* __restrict__ W,
                                              const float* __restrict__ bias,
                                              float* __restrict__ Y,
                                              int nrows, int K, int outF, int act) {
  __shared__ float Xt[64][65];
  __shared__ float Wt[64][65];
  int row0 = blockIdx.x * 64;
  int col0 = blockIdx.y * 64;
  int tid = threadIdx.x;
  int cg = (tid & 15) * 4;
  int rg = (tid >> 4) * 4;
  float acc[4][4] = {};
  for (int kk = 0; kk < K; kk += 64) {
#pragma unroll
    for (int i = 0; i < 16; ++i) {
      int idx = tid + 256 * i;
      int a = idx >> 6;
      int k = idx & 63;
      int gk = kk + k;
      float xv = 0.f;
      int gr = row0 + a;
      if (gr < nrows && gk < K) xv = X[(size_t)gr * K + gk];
      Xt[a][k] = xv;
      float wv = 0.f;
      int gc = col0 + a;
      if (gc < outF && gk < K) wv = W[(size_t)gc * K + gk];
      Wt[k][a] = wv;
    }
    __syncthreads();
#pragma unroll 8
    for (int k = 0; k < 64; ++k) {
      float w0 = Wt[k][cg + 0], w1 = Wt[k][cg + 1], w2 = Wt[k][cg + 2], w3 = Wt[k][cg + 3];
      float x0 = Xt[rg + 0][k], x1 = Xt[rg + 1][k], x2 = Xt[rg + 2][k], x3 = Xt[rg + 3][k];
      acc[0][0] += x0 * w0; acc[0][1] += x0 * w1; acc[0][2] += x0 * w2; acc[0][3] += x0 * w3;
      acc[1][0] += x1 * w0; acc[1][1] += x1 * w1; acc[1][2] += x1 * w2; acc[1][3] += x1 * w3;
      acc[2][0] += x2 * w0; acc[2][1] += x2 * w1; acc[2][2] += x2 * w2; acc[2][3] += x2 * w3;
      acc[3][0] += x3 * w0; acc[3][1] += x3 * w1; acc[3][2] += x3 * w2; acc[3][3] += x3 * w3;
    }
    __syncthreads();
  }
#pragma unroll
  for (int i = 0; i < 4; ++i) {
    int gr = row0 + rg + i;
    if (gr >= nrows) continue;
#pragma unroll
    for (int j = 0; j < 4; ++j) {
      int gc = col0 + cg + j;
      if (gc >= outF) continue;
      float v = acc[i][j];
      if (bias) v += bias[gc];
      if (act) v = eluf(v);
      Y[(size_t)gr * outF + gc] = v;
    }
  }
}

// ---------------- big GEMM (fine stages): 128x64 tile, BK=32, 8x4/thread ----------------
__global__ __launch_bounds__(256) void k_gemm2(const float* __restrict__ X,
                                               const float* __restrict__ W,
                                               const float* __restrict__ bias,
                                               float* __restrict__ Y,
                                               int nrows, int K, int outF, int act) {
  __shared__ float Xt[32][132];
  __shared__ float Wt[32][68];
  int row0 = blockIdx.x * 128;
  int col0 = blockIdx.y * 64;
  int tid = threadIdx.x;
  int tc = (tid & 15) * 4;
  int tr = (tid >> 4) * 8;
  float acc[8][4] = {};
  for (int kk = 0; kk < K; kk += 32) {
#pragma unroll
    for (int i = 0; i < 16; ++i) {
      int idx = tid + 256 * i;
      int k = idx & 31, r = idx >> 5;
      int gr = row0 + r, gk = kk + k;
      Xt[k][r] = (gr < nrows && gk < K) ? X[(size_t)gr * K + gk] : 0.f;
    }
#pragma unroll
    for (int i = 0; i < 8; ++i) {
      int idx = tid + 256 * i;
      int k = idx & 31, c = idx >> 5;
      int gc = col0 + c, gk = kk + k;
      Wt[k][c] = (gc < outF && gk < K) ? W[(size_t)gc * K + gk] : 0.f;
    }
    __syncthreads();
#pragma unroll 8
    for (int k = 0; k < 32; ++k) {
      float4 w = *(const float4*)&Wt[k][tc];
      float4 xa = *(const float4*)&Xt[k][tr];
      float4 xb = *(const float4*)&Xt[k][tr + 4];
      float xs[8] = {xa.x, xa.y, xa.z, xa.w, xb.x, xb.y, xb.z, xb.w};
      float ws4[4] = {w.x, w.y, w.z, w.w};
#pragma unroll
      for (int i = 0; i < 8; ++i)
#pragma unroll
        for (int j = 0; j < 4; ++j) acc[i][j] += xs[i] * ws4[j];
    }
    __syncthreads();
  }
#pragma unroll
  for (int i = 0; i < 8; ++i) {
    int gr = row0 + tr + i;
    if (gr >= nrows) continue;
    int gc = col0 + tc;
    float4 v;
    v.x = acc[i][0]; v.y = acc[i][1]; v.z = acc[i][2]; v.w = acc[i][3];
    if (bias) { v.x += bias[gc]; v.y += bias[gc + 1]; v.z += bias[gc + 2]; v.w += bias[gc + 3]; }
    if (act) { v.x = eluf(v.x); v.y = eluf(v.y); v.z = eluf(v.z); v.w = eluf(v.w); }
    if (gc + 3 < outF) {
      *(float4*)&Y[(size_t)gr * outF + gc] = v;
    } else {
      float vs[4] = {v.x, v.y, v.z, v.w};
      for (int j = 0; j < 4; ++j)
        if (gc + j < outF) Y[(size_t)gr * outF + gc + j] = vs[j];
    }
  }
}

// ---------------- fine aggregation F=64: wave/dst, fused self-loop+bias+ELU ----------------
__global__ __launch_bounds__(256) void k_agg_fine64(
    const int* __restrict__ rowptr, const int* __restrict__ csrc, const float* __restrict__ cnorm,
    const float* __restrict__ h, const float* __restrict__ dinv, const float* __restrict__ bias,
    float* __restrict__ out, int n) {
  int w = blockIdx.x * 4 + (threadIdx.x >> 6);
  if (w >= n) return;
  int lane = threadIdx.x & 63;
  int start = rowptr[w], end = rowptr[w + 1];
  float acc = 0.f;
  int e = start;
  for (; e + 3 < end; e += 4) {
    int s0 = csrc[e], s1 = csrc[e + 1], s2 = csrc[e + 2], s3 = csrc[e + 3];
    float n0 = cnorm[e], n1 = cnorm[e + 1], n2 = cnorm[e + 2], n3 = cnorm[e + 3];
    float v0 = h[(size_t)s0 * 64 + lane];
    float v1 = h[(size_t)s1 * 64 + lane];
    float v2 = h[(size_t)s2 * 64 + lane];
    float v3 = h[(size_t)s3 * 64 + lane];
    acc += n0 * v0 + n1 * v1 + n2 * v2 + n3 * v3;
  }
  for (; e < end; ++e) acc += cnorm[e] * h[(size_t)csrc[e] * 64 + lane];
  float dd = dinv[w]; dd *= dd;
  out[(size_t)w * 64 + lane] = eluf(acc + dd * h[(size_t)w * 64 + lane] + bias[lane]);
}

// ---------------- fine aggregation F=128: wave/dst, float2/lane, PURE LINEAR ----------------
// (agg before GEMM: agg(x) @ W.T == agg(x @ W.T); bias+ELU applied in the following GEMM)
__global__ __launch_bounds__(256) void k_agg_fine128(
    const int* __restrict__ rowptr, const int* __restrict__ csrc, const float* __restrict__ cnorm,
    const float2* __restrict__ h2, const float* __restrict__ dinv,
    float2* __restrict__ out2, int n) {
  int w = blockIdx.x * 4 + (threadIdx.x >> 6);
  if (w >= n) return;
  int lane = threadIdx.x & 63;
  int start = rowptr[w], end = rowptr[w + 1];
  float ax = 0.f, ay = 0.f;
  int e = start;
  for (; e + 3 < end; e += 4) {
    int s0 = csrc[e], s1 = csrc[e + 1], s2 = csrc[e + 2], s3 = csrc[e + 3];
    float n0 = cnorm[e], n1 = cnorm[e + 1], n2 = cnorm[e + 2], n3 = cnorm[e + 3];
    float2 v0 = h2[(size_t)s0 * 64 + lane];
    float2 v1 = h2[(size_t)s1 * 64 + lane];
    float2 v2 = h2[(size_t)s2 * 64 + lane];
    float2 v3 = h2[(size_t)s3 * 64 + lane];
    ax += n0 * v0.x + n1 * v1.x + n2 * v2.x + n3 * v3.x;
    ay += n0 * v0.y + n1 * v1.y + n2 * v2.y + n3 * v3.y;
  }
  for (; e < end; ++e) {
    float nm = cnorm[e];
    float2 v = h2[(size_t)csrc[e] * 64 + lane];
    ax += nm * v.x; ay += nm * v.y;
  }
  float dd = dinv[w]; dd *= dd;
  float2 hw = h2[(size_t)w * 64 + lane];
  float2 o;
  o.x = ax + dd * hw.x;
  o.y = ay + dd * hw.y;
  out2[(size_t)w * 64 + lane] = o;
}

// ---------------- coarse aggregation (block/dst) + optional fused FC ----------------
__global__ __launch_bounds__(256) void k_agg_coarse(int F,
    const int* __restrict__ rowptr, const int* __restrict__ csrc, const float* __restrict__ cnorm,
    const float* __restrict__ h, const float* __restrict__ dinv, const float* __restrict__ bias,
    float* __restrict__ out, int act) {
  int d = blockIdx.x;
  int lane = threadIdx.x & 63, wv = threadIdx.x >> 6;
  int start = rowptr[d], end = rowptr[d + 1];
  float acc0 = 0.f, acc1 = 0.f;
  for (int e = start + wv; e < end; e += 4) {
    int s = csrc[e];
    float nm = cnorm[e];
    if (lane < F) acc0 += nm * h[(size_t)s * F + lane];
    if (lane + 64 < F) acc1 += nm * h[(size_t)s * F + lane + 64];
  }
  __shared__ float red[4][128];
  if (lane < F) red[wv][lane] = acc0;
  if (lane + 64 < F) red[wv][lane + 64] = acc1;
  __syncthreads();
  if (wv == 0) {
#pragma unroll 2
    for (int j = 0; j < 2; ++j) {
      int c = lane + j * 64;
      if (c < F) {
        float v = red[0][c] + red[1][c] + red[2][c] + red[3][c];
        float dd = dinv[d] * dinv[d];
        v += dd * h[(size_t)d * F + c] + bias[c];
        if (act) v = eluf(v);
        out[(size_t)d * F + c] = v;
      }
    }
  }
}

__global__ __launch_bounds__(256) void k_agg_coarse_fc(int F,
    const int* __restrict__ rowptr, const int* __restrict__ csrc, const float* __restrict__ cnorm,
    const float* __restrict__ h, const float* __restrict__ dinv, const float* __restrict__ bias,
    const float* __restrict__ Wf, const float* __restrict__ bf, int outF2,
    float* __restrict__ out) {
  int d = blockIdx.x;
  int lane = threadIdx.x & 63, wv = threadIdx.x >> 6;
  int start = rowptr[d], end = rowptr[d + 1];
  float acc0 = 0.f, acc1 = 0.f;
  for (int e = start + wv; e < end; e += 4) {
    int s = csrc[e];
    float nm = cnorm[e];
    if (lane < F) acc0 += nm * h[(size_t)s * F + lane];
    if (lane + 64 < F) acc1 += nm * h[(size_t)s * F + lane + 64];
  }
  __shared__ float red[4][128];
  __shared__ __align__(16) float a_sh[128];
  if (lane < F) red[wv][lane] = acc0;
  if (lane + 64 < F) red[wv][lane + 64] = acc1;
  __syncthreads();
  if (wv == 0) {
#pragma unroll 2
    for (int j = 0; j < 2; ++j) {
      int c = lane + j * 64;
      if (c < F) {
        float v = red[0][c] + red[1][c] + red[2][c] + red[3][c];
        float dd = dinv[d] * dinv[d];
        a_sh[c] = eluf(v + dd * h[(size_t)d * F + c] + bias[c]);
      }
    }
  }
  __syncthreads();
  int j = threadIdx.x;
  if (j < outF2) {
    const float4* wr = (const float4*)(Wf + (size_t)j * F);
    const float4* ar = (const float4*)a_sh;
    float s = bf[j];
    for (int c = 0; c < (F >> 2); ++c) {
      float4 wv4 = wr[c];
      float4 av = ar[c];
      s += wv4.x * av.x + wv4.y * av.y + wv4.z * av.z + wv4.w * av.w;
    }
    out[(size_t)d * outF2 + j] = eluf(s);
  }
}

// ---------------- instance-norm stats ----------------
__global__ __launch_bounds__(256) void k_chanstats(const float* __restrict__ x, int n,
                                                   float* __restrict__ s, float* __restrict__ s2) {
  int ch = threadIdx.x;
  float a = 0.f, b = 0.f;
  for (int r = blockIdx.x; r < n; r += gridDim.x) {
    float v = x[(size_t)r * 256 + ch];
    a += v;
    b += v * v;
  }
  atomicAdd(&s[ch], a);
  atomicAdd(&s2[ch], b);
}

// ---------------- fused mu/rstd + normalize + cluster mean pool ----------------
__global__ __launch_bounds__(256) void k_pool(const float* __restrict__ x,
                                              const int* __restrict__ rowptr,
                                              const int* __restrict__ nodes,
                                              const float* __restrict__ sS,
                                              const float* __restrict__ sS2,
                                              float ninv,
                                              float* __restrict__ cx) {
  int c = blockIdx.x;
  int ch = threadIdx.x;
  float mu = sS[ch] * ninv;
  float var = sS2[ch] * ninv - mu * mu;
  float rstd = rsqrtf(var + 1e-5f);
  int start = rowptr[c], end = rowptr[c + 1];
  float s = 0.f;
  for (int i = start; i < end; ++i) s += x[(size_t)nodes[i] * 256 + ch];
  int cnt = end - start; if (cnt < 1) cnt = 1;
  float v = s / (float)cnt;
  cx[(size_t)c * 256 + ch] = (v - mu) * rstd;
}

// ---------------- o_feat = W_fcO @ g ----------------
__global__ __launch_bounds__(256) void k_matvec(const float* __restrict__ W,
                                                const float* __restrict__ g,
                                                float* __restrict__ out, int M, int K) {
  __shared__ __align__(16) float gs[2560];
  for (int i = threadIdx.x; i < K; i += 256) gs[i] = g[i];
  __syncthreads();
  int lane = threadIdx.x & 63, wv = threadIdx.x >> 6;
#pragma unroll
  for (int rr = 0; rr < 4; ++rr) {
    int row = blockIdx.x * 16 + wv * 4 + rr;
    if (row >= M) break;
    const float4* Wr = (const float4*)(W + (size_t)row * K);
    float acc = 0.f;
#pragma unroll
    for (int it = 0; it < 10; ++it) {
      float4 w4 = Wr[it * 64 + lane];
      float4 g4 = *(const float4*)&gs[it * 256 + lane * 4];
      acc += w4.x * g4.x + w4.y * g4.y + w4.z * g4.z + w4.w * g4.w;
    }
#pragma unroll
    for (int off = 32; off; off >>= 1) acc += __shfl_down(acc, off, 64);
    if (lane == 0) out[row] = acc;
  }
}

// ==================================================================================
extern "C" void kernel_launch(void* const* d_in, const int* in_sizes, int n_in,
                              void* d_out, int out_size, void* d_ws, size_t ws_size,
                              hipStream_t stream) {
  const float* x     = (const float*)d_in[0];
  const float* W_G1  = (const float*)d_in[1];
  const float* b_G1  = (const float*)d_in[2];
  const float* Wf_G1 = (const float*)d_in[3];
  const float* bf_G1 = (const float*)d_in[4];
  const float* W_G2  = (const float*)d_in[5];
  const float* b_G2  = (const float*)d_in[6];
  const float* Wf_G2 = (const float*)d_in[7];
  const float* bf_G2 = (const float*)d_in[8];
  const float* W_L1  = (const float*)d_in[9];
  const float* b_L1  = (const float*)d_in[10];
  const float* Wf_L1 = (const float*)d_in[11];
  const float* bf_L1 = (const float*)d_in[12];
  const float* W_L2  = (const float*)d_in[13];
  const float* b_L2  = (const float*)d_in[14];
  const float* Wf_L2 = (const float*)d_in[15];
  const float* bf_L2 = (const float*)d_in[16];
  const float* W_M1  = (const float*)d_in[17];
  const float* b_M1  = (const float*)d_in[18];
  const float* Wf_M1 = (const float*)d_in[19];
  const float* bf_M1 = (const float*)d_in[20];
  const float* W_O1  = (const float*)d_in[21];
  const float* b_O1  = (const float*)d_in[22];
  const float* W_fcO = (const float*)d_in[23];
  const int* edge    = (const int*)d_in[24];
  const int* cluster = (const int*)d_in[25];
  const int* cedge   = (const int*)d_in[27];

  const int E  = in_sizes[24] / 2;
  const int Ec = in_sizes[27] / 2;

  char* ws = (char*)d_ws;
  size_t off = 0;
  auto alloc = [&](size_t bytes) -> void* {
    void* p = ws + off;
    off = (off + bytes + 255) & ~(size_t)255;
    return p;
  };

  float* bufA = (float*)alloc((size_t)NN * 256 * 4);
  float* bufB = (float*)alloc((size_t)NN * 256 * 4);
  float* bufC = (float*)alloc((size_t)NN * 256 * 4);
  float* cx   = (float*)alloc((size_t)CC * 256 * 4);
  float* zA   = (float*)alloc((size_t)CC * 256 * 4);
  float* zB   = (float*)alloc((size_t)CC * 256 * 4);
  float* dinvF = (float*)alloc((size_t)NN * 4);
  float* dinvC = (float*)alloc((size_t)CC * 4);
  int* rowF  = (int*)alloc((size_t)(NN + 1) * 4);
  int* rowC  = (int*)alloc((size_t)(CC + 1) * 4);
  int* rowCl = (int*)alloc((size_t)(CC + 1) * 4);
  int* csrcF = (int*)alloc((size_t)E * 4);
  float* cnormF = (float*)alloc((size_t)E * 4);
  int* csrcC = (int*)alloc((size_t)Ec * 4);
  float* cnormC = (float*)alloc((size_t)Ec * 4);
  int* cnodes = (int*)alloc((size_t)NN * 4);
  // ---- contiguous zero region ----
  size_t zoff = off;
  int* degF  = (int*)alloc((size_t)NN * 4);
  int* fillF = (int*)alloc((size_t)NN * 4);
  int* degC  = (int*)alloc((size_t)CC * 4);
  int* fillC = (int*)alloc((size_t)CC * 4);
  int* degCl = (int*)alloc((size_t)CC * 4);
  int* fillCl = (int*)alloc((size_t)CC * 4);
  float* chanS  = (float*)alloc(256 * 4);
  float* chanS2 = (float*)alloc(256 * 4);
  size_t zbytes = off - zoff;

  float* g_out = (float*)d_out;          // [2560] g_feat
  float* o_out = (float*)d_out + 2560;   // [60000] o_feat

  auto cdiv = [](int a, int b) { return (a + b - 1) / b; };

  k_zero<<<cdiv((int)(zbytes / 16), 256), 256, 0, stream>>>((float4*)(ws + zoff), (int)(zbytes / 16));

  // ---- fused CSR build: counts -> scans(+dinv) -> scatters ----
  k_count3<<<cdiv(E + Ec + NN, 256), 256, 0, stream>>>(edge + E, E, degF,
                                                       cedge + Ec, Ec, degC,
                                                       cluster, NN, degCl);
  k_scan3<<<3, 1024, 0, stream>>>(degF, NN, rowF, dinvF,
                                  degC, CC, rowC, dinvC,
                                  degCl, CC, rowCl);
  k_scatter3<<<cdiv(E + Ec + NN, 256), 256, 0, stream>>>(
      edge, E, rowF, fillF, dinvF, csrcF, cnormF,
      cedge, Ec, rowC, fillC, dinvC, csrcC, cnormC,
      cluster, NN, rowCl, fillCl, cnodes);

  // ---- fine pipeline ----
  // h1 = x @ W_G1.T  [N,64]
  k_gemm2<<<dim3(cdiv(NN, 128), 1), 256, 0, stream>>>(x, W_G1, nullptr, bufA, NN, 128, 64, 0);
  // x1 = elu(agg(h1) + b_G1)  [N,64]
  k_agg_fine64<<<NN / 4, 256, 0, stream>>>(rowF, csrcF, cnormF, bufA, dinvF, b_G1, bufC, NN);
  // x2 = elu(x1 @ Wf_G1.T + bf)  [N,128]
  k_gemm2<<<dim3(cdiv(NN, 128), 2), 256, 0, stream>>>(bufC, Wf_G1, bf_G1, bufA, NN, 64, 128, 1);
  // a2 = agg(x2)  [N,128]   (agg commutes with the GCN linear: agg(x)W^T == agg(xW^T))
  k_agg_fine128<<<NN / 4, 256, 0, stream>>>(rowF, csrcF, cnormF, (const float2*)bufA, dinvF,
                                            (float2*)bufC, NN);
  // x3 = elu(a2 @ W_G2.T + b_G2)  [N,256]
  k_gemm2<<<dim3(cdiv(NN, 128), 4), 256, 0, stream>>>(bufC, W_G2, b_G2, bufB, NN, 128, 256, 1);
  // x4 = elu(x3 @ Wf_G2.T + bf)  [N,256]
  k_gemm2<<<dim3(cdiv(NN, 128), 4), 256, 0, stream>>>(bufB, Wf_G2, bf_G2, bufA, NN, 256, 256, 1);

  // ---- instance norm stats + fused pool ----
  k_chanstats<<<256, 256, 0, stream>>>(bufA, NN, chanS, chanS2);
  k_pool<<<CC, 256, 0, stream>>>(bufA, rowCl, cnodes, chanS, chanS2, 1.f / (float)NN, cx);

  // ---- coarse pipeline ----
  k_gemm<<<dim3(cdiv(CC, 64), 2), 256, 0, stream>>>(cx, W_L1, nullptr, zA, CC, 256, 128, 0);
  k_agg_coarse_fc<<<CC, 256, 0, stream>>>(128, rowC, csrcC, cnormC, zA, dinvC, b_L1,
                                          Wf_L1, bf_L1, 96, zB);
  k_gemm<<<dim3(cdiv(CC, 64), 1), 256, 0, stream>>>(zB, W_L2, nullptr, zA, CC, 96, 64, 0);
  k_agg_coarse_fc<<<CC, 256, 0, stream>>>(64, rowC, csrcC, cnormC, zA, dinvC, b_L2,
                                          Wf_L2, bf_L2, 32, zB);
  k_gemm<<<dim3(cdiv(CC, 64), 1), 256, 0, stream>>>(zB, W_M1, nullptr, zA, CC, 32, 16, 0);
  k_agg_coarse_fc<<<CC, 256, 0, stream>>>(16, rowC, csrcC, cnormC, zA, dinvC, b_M1,
                                          Wf_M1, bf_M1, 8, zB);
  k_gemm<<<dim3(cdiv(CC, 64), 1), 256, 0, stream>>>(zB, W_O1, nullptr, zA, CC, 8, 5, 0);
  k_agg_coarse<<<CC, 256, 0, stream>>>(5, rowC, csrcC, cnormC, zA, dinvC, b_O1, g_out, 0);

  // ---- o_feat = W_fcO @ g_feat ----
  k_matvec<<<cdiv(3 * NN, 16), 256, 0, stream>>>(W_fcO, g_out, o_out, 3 * NN, 2560);
}